// Round 13
// baseline (922.145 us; speedup 1.0000x reference)
//
#include <hip/hip_runtime.h>
#include <math.h>

// Problem constants (match reference)
#define BATCH 1024
#define NV    64      // N_VARS
#define MC    256     // M_CLAUSES
#define KD    12      // K_DIM
#define PI_F  3.14159265358979323846f

// ws/LDS layout (floats):
//   NR rows 64x68: row q = C-row of var v = nv(q) = (q+1)%64+1, slot j =
//     C[v][j+1], with cols {v-2, v-1, v} (wrapped in 1..64) PRE-ZEROED.
//   c0N[64]  at C0OFF : C[v][0]
//   DgA[64]  at DGAOFF: DgA[v-1] = C[v][prev1(v)]  (prev1(1)=64)
//   DgB[64]  at DGBOFF: DgB[v-1] = C[v][prev2(v)]  (prev2(1)=63, prev2(2)=64)
#define CBUF   4544
#define C0OFF  4352
#define DGAOFF 4416
#define DGBOFF 4480

typedef float f2 __attribute__((ext_vector_type(2)));

// ---- DPP add helpers (intrinsic form: bound_ctrl=true, old=0 -> the
// canonical GCNDPPCombine-fusable pattern; compiler inserts required DPP
// hazard wait-states). 0xB1 qp xor1, 0x4E qp xor2, 0x124 row_ror:4,
// 0x128 row_ror:8, 0x142 row_bcast15, 0x143 row_bcast31.
template <int CTRL>
__device__ __forceinline__ float dpp_addf(float x) {
  int y = __builtin_amdgcn_update_dpp(0, __float_as_int(x), CTRL, 0xF, 0xF, true);
  return x + __int_as_float(y);
}
__device__ __forceinline__ float allreduce16(float x) {
  x = dpp_addf<0xB1>(x);
  x = dpp_addf<0x4E>(x);
  x = dpp_addf<0x124>(x);
  x = dpp_addf<0x128>(x);
  return x;
}
__device__ __forceinline__ float readlane63(float x) {
  return __int_as_float(__builtin_amdgcn_readlane(__float_as_int(x), 63));
}

// ---- Kernel 1: Gram rows (pre-zeroed excl. columns) + c0/dgA/dgB tables ----
__global__ void compute_C_kernel(const float* __restrict__ S,
                                 const float* __restrict__ w,
                                 float* __restrict__ Cg, int nsplit) {
  const int q = blockIdx.x;
  const int mc = blockIdx.y;
  const int j = threadIdx.x;  // column 0..64
  if (j > NV) return;
  const int v = (q + 1) % 64 + 1;
  const int mlen = MC / nsplit;
  const int m0 = mc * mlen;
  float a0 = 0.f, a1 = 0.f, a2 = 0.f, a3 = 0.f;
  for (int m = m0; m < m0 + mlen; m += 4) {
    const float w0 = w[m], w1 = w[m + 1], w2 = w[m + 2], w3 = w[m + 3];
    a0 = fmaf(S[(m + 0) * (NV + 1) + v] * w0 * w0, S[(m + 0) * (NV + 1) + j], a0);
    a1 = fmaf(S[(m + 1) * (NV + 1) + v] * w1 * w1, S[(m + 1) * (NV + 1) + j], a1);
    a2 = fmaf(S[(m + 2) * (NV + 1) + v] * w2 * w2, S[(m + 2) * (NV + 1) + j], a2);
    a3 = fmaf(S[(m + 3) * (NV + 1) + v] * w3 * w3, S[(m + 3) * (NV + 1) + j], a3);
  }
  const float acc = (a0 + a1) + (a2 + a3);
  float* buf = Cg + mc * CBUF;
  const int p1 = (v == 1) ? 64 : (v - 1);
  const int p2 = (v == 1) ? 63 : (v == 2) ? 64 : (v - 2);
  if (j == 0) buf[C0OFF + q] = acc;
  if (j == p1) buf[DGAOFF + (v - 1)] = acc;
  if (j == p2) buf[DGBOFF + (v - 1)] = acc;
  if (j > 0) {
    // pre-zero the columns Phase B must exclude: {v-2, v-1, v}
    const float st = (j == v || j == p1 || j == p2) ? 0.f : acc;
    buf[q * 68 + (j - 1)] = st;
  }
}

// ---- Kernel 2: two-column-deferred mixing, packed-fp32, full sweep unroll --
// Block = 256 thr = 4 waves = 4 batches, shared LDS C. Wave: kq = l>>4 owns
// k-triple {3kq..3kq+2}; n16 = l&15 owns vars 4*n16+1..4*n16+4.
// Per lane: V01[4] (f2: k0,k1) + V2[4] (k2). Carried: P01/P2 = Q_i (dot
// missing cols i-1,i-2), vp1*/vp2* = u_{i-1}/u_{i-2}.
// Step i: B) Q_{i+1} from pre-zeroed row via v_pk_fma_f32; A) g = P + DgA*vp1
// + DgB*vp2 (pk) -> norm chain -> v_new; C) delayed writeback of u_{i-1}.
// The 16-group sweep body is FULLY UNROLLED (~22 KB < 32 KB I$): owner masks
// become compile-time (n16==const), hoistable across the 12-sweep loop, and
// loop-carried rotation movs vanish via register renaming.
__global__ __launch_bounds__(256, 1) void mixing_kernel(
    const float* __restrict__ z, const float* __restrict__ r,
    const float* __restrict__ Cg, const int* __restrict__ max_iter_p,
    float* __restrict__ out, int nsplit) {
  __shared__ float Ls[CBUF];  // 18176 B

  const int t = threadIdx.x;
  const int l = t & 63;
  const int kq = l >> 4;
  const int n16 = l & 15;
  const int b = blockIdx.x * 4 + (t >> 6);
  const int max_iter = max_iter_p[0];

  // stage (and m-split-reduce) C into LDS
  {
    const float4* src = (const float4*)Cg;
    float4* dst = (float4*)Ls;
    for (int idx = t; idx < CBUF / 4; idx += 256) {
      float4 a = src[idx];
      for (int u = 1; u < nsplit; ++u) {
        const float4 p = src[u * (CBUF / 4) + idx];
        a.x += p.x; a.y += p.y; a.z += p.z; a.w += p.w;
      }
      dst[idx] = a;
    }
  }

  const float row0 = (kq == 0) ? 1.f : 0.f;

  // ---- init: V[n] = -cos(pi z) e0 + sin(pi z) * r_perp_hat ----
  f2 V01[4];
  float V2[4];
  #pragma unroll
  for (int s = 0; s < 4; ++s) {
    const int n = 4 * n16 + s;
    const float zv = z[b * NV + n];
    float rp[3];
    float ssp = 0.f;
    #pragma unroll
    for (int j = 0; j < 3; ++j) {
      const int k = 3 * kq + j;
      rp[j] = (k == 0) ? 0.f : r[(b * NV + n) * KD + k];
      ssp = fmaf(rp[j], rp[j], ssp);
    }
    ssp += __shfl_xor(ssp, 16, 64);
    ssp += __shfl_xor(ssp, 32, 64);
    const float inv = 1.f / fmaxf(sqrtf(ssp), 1e-8f);
    float sn, cs;
    sincosf(PI_F * zv, &sn, &cs);
    float vv[3];
    #pragma unroll
    for (int j = 0; j < 3; ++j) {
      const int k = 3 * kq + j;
      vv[j] = (k == 0) ? -cs : sn * rp[j] * inv;
    }
    V01[s].x = vv[0];
    V01[s].y = vv[1];
    V2[s] = vv[2];
  }

  __syncthreads();

  const float4* C4   = (const float4*)Ls;               // [q*17 + n16]
  const float4* C04  = (const float4*)(Ls + C0OFF);     // [g]
  const float4* DgA4 = (const float4*)(Ls + DGAOFF);    // [g]
  const float4* DgB4 = (const float4*)(Ls + DGBOFF);    // [g]

  f2 P01, vp1_01, vp2_01;
  float P2, vp1_2, vp2_2;

  // ---- prologue: Q_1 from pre-zeroed row NR[63] (= C[1]);
  //      vp1 = V_init[var64] (slot63), vp2 = V_init[var63] (slot62) ----
  {
    const float4 ce = C4[63 * 17 + n16];
    const float c0 = Ls[C0OFF + 63];
    f2 q01 = ce.x * V01[0];
    float q2 = ce.x * V2[0];
    q01 = __builtin_elementwise_fma((f2){ce.y, ce.y}, V01[1], q01);
    q2 = fmaf(ce.y, V2[1], q2);
    q01 = __builtin_elementwise_fma((f2){ce.z, ce.z}, V01[2], q01);
    q2 = fmaf(ce.z, V2[2], q2);
    q01 = __builtin_elementwise_fma((f2){ce.w, ce.w}, V01[3], q01);
    q2 = fmaf(ce.w, V2[3], q2);
    q01.x = allreduce16(q01.x);
    q01.y = allreduce16(q01.y);
    q2 = allreduce16(q2);
    q01.x = fmaf(row0, c0, q01.x);
    P01 = q01; P2 = q2;
    const int src = l | 15;  // this row's lane 15
    vp1_01.x = __shfl(V01[3].x, src, 64);
    vp1_01.y = __shfl(V01[3].y, src, 64);
    vp1_2    = __shfl(V2[3],    src, 64);
    vp2_01.x = __shfl(V01[2].x, src, 64);
    vp2_01.y = __shfl(V01[2].y, src, 64);
    vp2_2    = __shfl(V2[2],    src, 64);
  }

  float4 cbA[4], cbB[4], c0A, c0B, daA, daB, dbA, dbB;

  auto prefetch = [&](float4 cb[4], float4& c0b, float4& dab, float4& dbb, int g) {
    #pragma unroll
    for (int s = 0; s < 4; ++s) cb[s] = C4[(4 * g + s) * 17 + n16];
    c0b = C04[g];
    dab = DgA4[g];
    dbb = DgB4[g];
  };

  auto do_group = [&](int ii, const float4 cb[4], const float4& c0b,
                      const float4& dab, const float4& dbb) {
    const bool own  = (n16 == ii);                 // compile-time ii: hoisted
    const bool ownP = (n16 == ((ii + 15) & 15));
    const float* c0p = &c0b.x;
    const float* dap = &dab.x;
    const float* dbp = &dbb.x;
    #pragma unroll
    for (int s = 0; s < 4; ++s) {
      const float4 ce = cb[s];
      const float db = dbp[s], da = dap[s];

      // ---- Phase A start: the true recurrence (g, n2 partial) ----
      f2 g01 = __builtin_elementwise_fma((f2){db, db}, vp2_01, P01);
      float g2 = fmaf(db, vp2_2, P2);
      g01 = __builtin_elementwise_fma((f2){da, da}, vp1_01, g01);
      g2 = fmaf(da, vp1_2, g2);

      // ---- Phase B products (independent; packed k0k1 + scalar k2) ----
      f2 q01 = ce.x * V01[0];
      float q2 = ce.x * V2[0];
      q01 = __builtin_elementwise_fma((f2){ce.y, ce.y}, V01[1], q01);
      q2 = fmaf(ce.y, V2[1], q2);
      q01 = __builtin_elementwise_fma((f2){ce.z, ce.z}, V01[2], q01);
      q2 = fmaf(ce.z, V2[2], q2);
      q01 = __builtin_elementwise_fma((f2){ce.w, ce.w}, V01[3], q01);
      q2 = fmaf(ce.w, V2[3], q2);

      float n2p = g01.x * g01.x;
      n2p = fmaf(g01.y, g01.y, n2p);
      n2p = fmaf(g2, g2, n2p);

      // ---- cross-lane: A's bcast chain + B's butterflies, hop-major ----
      n2p = dpp_addf<0x142>(n2p);                 // A: row1+=row0, row3+=row2
      q01.x = dpp_addf<0xB1>(q01.x);              // B hop 1
      q01.y = dpp_addf<0xB1>(q01.y);
      q2 = dpp_addf<0xB1>(q2);
      n2p = dpp_addf<0x143>(n2p);                 // A: lane63 = total
      q01.x = dpp_addf<0x4E>(q01.x);              // B hop 2
      q01.y = dpp_addf<0x4E>(q01.y);
      q2 = dpp_addf<0x4E>(q2);
      const float n2 = readlane63(n2p);           // A tail starts
      q01.x = dpp_addf<0x124>(q01.x);             // B hop 3
      q01.y = dpp_addf<0x124>(q01.y);
      q2 = dpp_addf<0x124>(q2);
      const float inv = __builtin_amdgcn_rsqf(fmaxf(n2, 1e-16f));
      q01.x = dpp_addf<0x128>(q01.x);             // B hop 4
      q01.y = dpp_addf<0x128>(q01.y);
      q2 = dpp_addf<0x128>(q2);
      const f2 vn01 = g01 * (f2){-inv, -inv};     // == -g * inv (exact)
      const float vn2 = -g2 * inv;
      q01.x = fmaf(row0, c0p[s], q01.x);          // e0 term -> k=0 only

      // ---- Phase C: delayed writeback of u_{i-1} (held in vp1) ----
      if (s == 0) {
        V01[3].x = ownP ? vp1_01.x : V01[3].x;
        V01[3].y = ownP ? vp1_01.y : V01[3].y;
        V2[3]    = ownP ? vp1_2    : V2[3];
      } else {
        V01[s - 1].x = own ? vp1_01.x : V01[s - 1].x;
        V01[s - 1].y = own ? vp1_01.y : V01[s - 1].y;
        V2[s - 1]    = own ? vp1_2    : V2[s - 1];
      }

      // rotate carried state (renamed by unroll)
      vp2_01 = vp1_01; vp2_2 = vp1_2;
      vp1_01 = vn01;   vp1_2 = vn2;
      P01 = q01;       P2 = q2;
    }
  };

  prefetch(cbA, c0A, daA, dbA, 0);

  // ---- sweeps: 16-group body fully unrolled (constant ii everywhere) ----
  for (int it = 0; it < max_iter; ++it) {
    #pragma unroll
    for (int ih = 0; ih < 8; ++ih) {
      prefetch(cbB, c0B, daB, dbB, 2 * ih + 1);
      do_group(2 * ih, cbA, c0A, daA, dbA);
      prefetch(cbA, c0A, daA, dbA, (2 * ih + 2) & 15);
      do_group(2 * ih + 1, cbB, c0B, daB, dbB);
    }
  }

  // final pending writeback: u_64 still in vp1 -> slot 63 (lane 15, V[3])
  {
    const bool l15 = (n16 == 15);
    V01[3].x = l15 ? vp1_01.x : V01[3].x;
    V01[3].y = l15 ? vp1_01.y : V01[3].y;
    V2[3]    = l15 ? vp1_2    : V2[3];
  }

  // ---- epilogue: kq==0 lanes hold k=0 ----
  if (kq == 0) {
    float4 o;
    float* op = &o.x;
    #pragma unroll
    for (int s = 0; s < 4; ++s) {
      float cv = -V01[s].x;
      cv = fminf(fmaxf(cv, -1.f + 1e-6f), 1.f - 1e-6f);
      op[s] = acosf(cv) * (1.f / PI_F);
    }
    ((float4*)(out + b * NV))[n16] = o;
  }
}

extern "C" void kernel_launch(void* const* d_in, const int* in_sizes, int n_in,
                              void* d_out, int out_size, void* d_ws, size_t ws_size,
                              hipStream_t stream) {
  const float* z = (const float*)d_in[0];
  const float* S = (const float*)d_in[1];
  const float* w = (const float*)d_in[2];
  const float* r = (const float*)d_in[3];
  const int* max_iter = (const int*)d_in[4];
  float* Cg = (float*)d_ws;

  const int nsplit = (ws_size >= (size_t)8 * CBUF * 4) ? 8
                   : (ws_size >= (size_t)4 * CBUF * 4) ? 4 : 1;
  compute_C_kernel<<<dim3(NV, nsplit), 128, 0, stream>>>(S, w, Cg, nsplit);
  mixing_kernel<<<BATCH / 4, 256, 0, stream>>>(z, r, Cg, max_iter,
                                               (float*)d_out, nsplit);
}

// Round 14
// 148.265 us; speedup vs baseline: 6.2196x; 6.2196x over previous
//
#include <hip/hip_runtime.h>
#include <math.h>

// Problem constants (match reference)
#define BATCH 1024
#define NV    64      // N_VARS
#define MC    256     // M_CLAUSES
#define KD    12      // K_DIM
#define PI_F  3.14159265358979323846f

// ws/LDS layout (floats):
//   NR rows 64x68: row q = C-row of var v = nv(q) = (q+1)%64+1, slot j =
//     C[v][j+1], with cols {v-2, v-1, v} (wrapped in 1..64) PRE-ZEROED.
//   c0N[64]  at C0OFF : C[v][0]
//   DgA[64]  at DGAOFF: DgA[v-1] = C[v][prev1(v)]  (prev1(1)=64)
//   DgB[64]  at DGBOFF: DgB[v-1] = C[v][prev2(v)]  (prev2(1)=63, prev2(2)=64)
#define CBUF   4544
#define C0OFF  4352
#define DGAOFF 4416
#define DGBOFF 4480

typedef float f2 __attribute__((ext_vector_type(2)));

// ---- DPP add helpers (intrinsic form: bound_ctrl=true, old=0 -> the
// canonical GCNDPPCombine-fusable pattern; compiler inserts required DPP
// hazard wait-states). 0xB1 qp xor1, 0x4E qp xor2, 0x124 row_ror:4,
// 0x128 row_ror:8, 0x142 row_bcast15, 0x143 row_bcast31.
template <int CTRL>
__device__ __forceinline__ float dpp_addf(float x) {
  int y = __builtin_amdgcn_update_dpp(0, __float_as_int(x), CTRL, 0xF, 0xF, true);
  return x + __int_as_float(y);
}
__device__ __forceinline__ float allreduce16(float x) {
  x = dpp_addf<0xB1>(x);
  x = dpp_addf<0x4E>(x);
  x = dpp_addf<0x124>(x);
  x = dpp_addf<0x128>(x);
  return x;
}
__device__ __forceinline__ float readlane63(float x) {
  return __int_as_float(__builtin_amdgcn_readlane(__float_as_int(x), 63));
}

// ---- Kernel 1: Gram rows (pre-zeroed excl. columns) + c0/dgA/dgB tables ----
__global__ void compute_C_kernel(const float* __restrict__ S,
                                 const float* __restrict__ w,
                                 float* __restrict__ Cg, int nsplit) {
  const int q = blockIdx.x;
  const int mc = blockIdx.y;
  const int j = threadIdx.x;  // column 0..64
  if (j > NV) return;
  const int v = (q + 1) % 64 + 1;
  const int mlen = MC / nsplit;
  const int m0 = mc * mlen;
  float a0 = 0.f, a1 = 0.f, a2 = 0.f, a3 = 0.f;
  for (int m = m0; m < m0 + mlen; m += 4) {
    const float w0 = w[m], w1 = w[m + 1], w2 = w[m + 2], w3 = w[m + 3];
    a0 = fmaf(S[(m + 0) * (NV + 1) + v] * w0 * w0, S[(m + 0) * (NV + 1) + j], a0);
    a1 = fmaf(S[(m + 1) * (NV + 1) + v] * w1 * w1, S[(m + 1) * (NV + 1) + j], a1);
    a2 = fmaf(S[(m + 2) * (NV + 1) + v] * w2 * w2, S[(m + 2) * (NV + 1) + j], a2);
    a3 = fmaf(S[(m + 3) * (NV + 1) + v] * w3 * w3, S[(m + 3) * (NV + 1) + j], a3);
  }
  const float acc = (a0 + a1) + (a2 + a3);
  float* buf = Cg + mc * CBUF;
  const int p1 = (v == 1) ? 64 : (v - 1);
  const int p2 = (v == 1) ? 63 : (v == 2) ? 64 : (v - 2);
  if (j == 0) buf[C0OFF + q] = acc;
  if (j == p1) buf[DGAOFF + (v - 1)] = acc;
  if (j == p2) buf[DGBOFF + (v - 1)] = acc;
  if (j > 0) {
    // pre-zero the columns Phase B must exclude: {v-2, v-1, v}
    const float st = (j == v || j == p1 || j == p2) ? 0.f : acc;
    buf[q * 68 + (j - 1)] = st;
  }
}

// ---- Kernel 2: two-column-deferred mixing, packed-fp32 k-pairs -------------
// (R12 structure — best known: mixing ~90 us, VGPR 40, no spills.)
// Block = 256 thr = 4 waves = 4 batches, shared LDS C. Wave: kq = l>>4 owns
// k-triple {3kq..3kq+2}; n16 = l&15 owns vars 4*n16+1..4*n16+4.
// Per lane: V01[4] (f2: k0,k1) + V2[4] (k2). Carried: P01/P2 = Q_i (dot
// missing cols i-1,i-2), vp1*/vp2* = u_{i-1}/u_{i-2}.
// Step i: B) Q_{i+1} from pre-zeroed row via v_pk_fma_f32 (8 slots vs 12);
// A) g = P + DgA*vp1 + DgB*vp2 (pk) -> norm chain -> v_new; C) delayed
// writeback of u_{i-1}. DPP hops act on the pair's subregisters in place.
// NOTE (R13 lesson): do NOT fully unroll the 16-group sweep — live prefetch
// state balloons to VGPR 256 and spills to scratch (951 us, 10x regression).
__global__ __launch_bounds__(256, 1) void mixing_kernel(
    const float* __restrict__ z, const float* __restrict__ r,
    const float* __restrict__ Cg, const int* __restrict__ max_iter_p,
    float* __restrict__ out, int nsplit) {
  __shared__ float Ls[CBUF];  // 18176 B

  const int t = threadIdx.x;
  const int l = t & 63;
  const int kq = l >> 4;
  const int n16 = l & 15;
  const int b = blockIdx.x * 4 + (t >> 6);
  const int max_iter = max_iter_p[0];

  // stage (and m-split-reduce) C into LDS
  {
    const float4* src = (const float4*)Cg;
    float4* dst = (float4*)Ls;
    for (int idx = t; idx < CBUF / 4; idx += 256) {
      float4 a = src[idx];
      for (int u = 1; u < nsplit; ++u) {
        const float4 p = src[u * (CBUF / 4) + idx];
        a.x += p.x; a.y += p.y; a.z += p.z; a.w += p.w;
      }
      dst[idx] = a;
    }
  }

  const float row0 = (kq == 0) ? 1.f : 0.f;

  // ---- init: V[n] = -cos(pi z) e0 + sin(pi z) * r_perp_hat ----
  f2 V01[4];
  float V2[4];
  #pragma unroll
  for (int s = 0; s < 4; ++s) {
    const int n = 4 * n16 + s;
    const float zv = z[b * NV + n];
    float rp[3];
    float ssp = 0.f;
    #pragma unroll
    for (int j = 0; j < 3; ++j) {
      const int k = 3 * kq + j;
      rp[j] = (k == 0) ? 0.f : r[(b * NV + n) * KD + k];
      ssp = fmaf(rp[j], rp[j], ssp);
    }
    ssp += __shfl_xor(ssp, 16, 64);
    ssp += __shfl_xor(ssp, 32, 64);
    const float inv = 1.f / fmaxf(sqrtf(ssp), 1e-8f);
    float sn, cs;
    sincosf(PI_F * zv, &sn, &cs);
    float vv[3];
    #pragma unroll
    for (int j = 0; j < 3; ++j) {
      const int k = 3 * kq + j;
      vv[j] = (k == 0) ? -cs : sn * rp[j] * inv;
    }
    V01[s].x = vv[0];
    V01[s].y = vv[1];
    V2[s] = vv[2];
  }

  __syncthreads();

  const float4* C4   = (const float4*)Ls;               // [q*17 + n16]
  const float4* C04  = (const float4*)(Ls + C0OFF);     // [g]
  const float4* DgA4 = (const float4*)(Ls + DGAOFF);    // [g]
  const float4* DgB4 = (const float4*)(Ls + DGBOFF);    // [g]

  f2 P01, vp1_01, vp2_01;
  float P2, vp1_2, vp2_2;

  // ---- prologue: Q_1 from pre-zeroed row NR[63] (= C[1]);
  //      vp1 = V_init[var64] (slot63), vp2 = V_init[var63] (slot62) ----
  {
    const float4 ce = C4[63 * 17 + n16];
    const float c0 = Ls[C0OFF + 63];
    f2 q01 = ce.x * V01[0];
    float q2 = ce.x * V2[0];
    q01 = __builtin_elementwise_fma((f2){ce.y, ce.y}, V01[1], q01);
    q2 = fmaf(ce.y, V2[1], q2);
    q01 = __builtin_elementwise_fma((f2){ce.z, ce.z}, V01[2], q01);
    q2 = fmaf(ce.z, V2[2], q2);
    q01 = __builtin_elementwise_fma((f2){ce.w, ce.w}, V01[3], q01);
    q2 = fmaf(ce.w, V2[3], q2);
    q01.x = allreduce16(q01.x);
    q01.y = allreduce16(q01.y);
    q2 = allreduce16(q2);
    q01.x = fmaf(row0, c0, q01.x);
    P01 = q01; P2 = q2;
    const int src = l | 15;  // this row's lane 15
    vp1_01.x = __shfl(V01[3].x, src, 64);
    vp1_01.y = __shfl(V01[3].y, src, 64);
    vp1_2    = __shfl(V2[3],    src, 64);
    vp2_01.x = __shfl(V01[2].x, src, 64);
    vp2_01.y = __shfl(V01[2].y, src, 64);
    vp2_2    = __shfl(V2[2],    src, 64);
  }

  float4 cbA[4], cbB[4], c0A, c0B, daA, daB, dbA, dbB;

  auto prefetch = [&](float4 cb[4], float4& c0b, float4& dab, float4& dbb, int g) {
    #pragma unroll
    for (int s = 0; s < 4; ++s) cb[s] = C4[(4 * g + s) * 17 + n16];
    c0b = C04[g];
    dab = DgA4[g];
    dbb = DgB4[g];
  };

  auto do_group = [&](int ii, const float4 cb[4], const float4& c0b,
                      const float4& dab, const float4& dbb) {
    const bool own  = (n16 == ii);
    const bool ownP = (n16 == ((ii + 15) & 15));
    const float* c0p = &c0b.x;
    const float* dap = &dab.x;
    const float* dbp = &dbb.x;
    #pragma unroll
    for (int s = 0; s < 4; ++s) {
      const float4 ce = cb[s];
      const float db = dbp[s], da = dap[s];

      // ---- Phase A start: the true recurrence (g, n2 partial) ----
      f2 g01 = __builtin_elementwise_fma((f2){db, db}, vp2_01, P01);
      float g2 = fmaf(db, vp2_2, P2);
      g01 = __builtin_elementwise_fma((f2){da, da}, vp1_01, g01);
      g2 = fmaf(da, vp1_2, g2);

      // ---- Phase B products (independent; packed k0k1 + scalar k2) ----
      f2 q01 = ce.x * V01[0];
      float q2 = ce.x * V2[0];
      q01 = __builtin_elementwise_fma((f2){ce.y, ce.y}, V01[1], q01);
      q2 = fmaf(ce.y, V2[1], q2);
      q01 = __builtin_elementwise_fma((f2){ce.z, ce.z}, V01[2], q01);
      q2 = fmaf(ce.z, V2[2], q2);
      q01 = __builtin_elementwise_fma((f2){ce.w, ce.w}, V01[3], q01);
      q2 = fmaf(ce.w, V2[3], q2);

      float n2p = g01.x * g01.x;
      n2p = fmaf(g01.y, g01.y, n2p);
      n2p = fmaf(g2, g2, n2p);

      // ---- cross-lane: A's bcast chain + B's butterflies, hop-major ----
      n2p = dpp_addf<0x142>(n2p);                 // A: row1+=row0, row3+=row2
      q01.x = dpp_addf<0xB1>(q01.x);              // B hop 1
      q01.y = dpp_addf<0xB1>(q01.y);
      q2 = dpp_addf<0xB1>(q2);
      n2p = dpp_addf<0x143>(n2p);                 // A: lane63 = total
      q01.x = dpp_addf<0x4E>(q01.x);              // B hop 2
      q01.y = dpp_addf<0x4E>(q01.y);
      q2 = dpp_addf<0x4E>(q2);
      const float n2 = readlane63(n2p);           // A tail starts
      q01.x = dpp_addf<0x124>(q01.x);             // B hop 3
      q01.y = dpp_addf<0x124>(q01.y);
      q2 = dpp_addf<0x124>(q2);
      const float inv = __builtin_amdgcn_rsqf(fmaxf(n2, 1e-16f));
      q01.x = dpp_addf<0x128>(q01.x);             // B hop 4
      q01.y = dpp_addf<0x128>(q01.y);
      q2 = dpp_addf<0x128>(q2);
      const f2 vn01 = g01 * (f2){-inv, -inv};     // == -g * inv (exact)
      const float vn2 = -g2 * inv;
      q01.x = fmaf(row0, c0p[s], q01.x);          // e0 term -> k=0 only

      // ---- Phase C: delayed writeback of u_{i-1} (held in vp1) ----
      if (s == 0) {
        V01[3].x = ownP ? vp1_01.x : V01[3].x;
        V01[3].y = ownP ? vp1_01.y : V01[3].y;
        V2[3]    = ownP ? vp1_2    : V2[3];
      } else {
        V01[s - 1].x = own ? vp1_01.x : V01[s - 1].x;
        V01[s - 1].y = own ? vp1_01.y : V01[s - 1].y;
        V2[s - 1]    = own ? vp1_2    : V2[s - 1];
      }

      // rotate carried state (renamed by unroll)
      vp2_01 = vp1_01; vp2_2 = vp1_2;
      vp1_01 = vn01;   vp1_2 = vn2;
      P01 = q01;       P2 = q2;
    }
  };

  prefetch(cbA, c0A, daA, dbA, 0);

  // ---- sweeps (groups of 4 steps; ping-pong prefetch, unroll by 2) ----
  for (int it = 0; it < max_iter; ++it) {
    for (int ih = 0; ih < 8; ++ih) {
      prefetch(cbB, c0B, daB, dbB, 2 * ih + 1);
      do_group(2 * ih, cbA, c0A, daA, dbA);
      prefetch(cbA, c0A, daA, dbA, (2 * ih + 2) & 15);
      do_group(2 * ih + 1, cbB, c0B, daB, dbB);
    }
  }

  // final pending writeback: u_64 still in vp1 -> slot 63 (lane 15, V[3])
  {
    const bool l15 = (n16 == 15);
    V01[3].x = l15 ? vp1_01.x : V01[3].x;
    V01[3].y = l15 ? vp1_01.y : V01[3].y;
    V2[3]    = l15 ? vp1_2    : V2[3];
  }

  // ---- epilogue: kq==0 lanes hold k=0 ----
  if (kq == 0) {
    float4 o;
    float* op = &o.x;
    #pragma unroll
    for (int s = 0; s < 4; ++s) {
      float cv = -V01[s].x;
      cv = fminf(fmaxf(cv, -1.f + 1e-6f), 1.f - 1e-6f);
      op[s] = acosf(cv) * (1.f / PI_F);
    }
    ((float4*)(out + b * NV))[n16] = o;
  }
}

extern "C" void kernel_launch(void* const* d_in, const int* in_sizes, int n_in,
                              void* d_out, int out_size, void* d_ws, size_t ws_size,
                              hipStream_t stream) {
  const float* z = (const float*)d_in[0];
  const float* S = (const float*)d_in[1];
  const float* w = (const float*)d_in[2];
  const float* r = (const float*)d_in[3];
  const int* max_iter = (const int*)d_in[4];
  float* Cg = (float*)d_ws;

  const int nsplit = (ws_size >= (size_t)8 * CBUF * 4) ? 8
                   : (ws_size >= (size_t)4 * CBUF * 4) ? 4 : 1;
  compute_C_kernel<<<dim3(NV, nsplit), 128, 0, stream>>>(S, w, Cg, nsplit);
  mixing_kernel<<<BATCH / 4, 256, 0, stream>>>(z, r, Cg, max_iter,
                                               (float*)d_out, nsplit);
}